// Round 7
// baseline (248.650 us; speedup 1.0000x reference)
//
#include <hip/hip_runtime.h>
#include <hip/hip_cooperative_groups.h>
#include <cstdint>
#include <cstddef>

namespace cg = cooperative_groups;

#define NN 8192          // nodes
#define DD 128           // feature dim (in == out)
#define RCAP 96          // raw per-row CSR capacity (max raw degree ~66 on Binomial(262144,1/8192))
#define WPR (NN / 32)    // fallback bitmap words per row

// ============================================================================
// FUSED cooperative kernel: A zero cnt | B linear ∥ scatter | C dedup | D agg
// ============================================================================
__global__ __launch_bounds__(256, 4) void fused_kernel(
    const float* __restrict__ x, const int* __restrict__ ei,
    const float* __restrict__ Wm, const float* __restrict__ bias,
    float* __restrict__ out,
    int* __restrict__ cnt, int* __restrict__ ucnt,
    int* __restrict__ adj, int* __restrict__ uadj,
    float* __restrict__ h, int E)
{
    cg::grid_group grid = cg::this_grid();
    __shared__ __align__(16) char smem[21632];   // union across phases (max: linear 21504B)
    const int tid = threadIdx.x;
    const int bid = blockIdx.x;
    const int G = gridDim.x;

    // ---------------- A: zero raw counts (32 KB)
    for (int i = bid * 256 + tid; i < NN; i += G * 256) cnt[i] = 0;
    grid.sync();

    // ---------------- B: linear on first G/4 blocks, CSR scatter on the rest
    const int Glin = G >> 2;
    if (bid < Glin) {
        float* Wl = (float*)smem;                    // [32][132]
        float* xl = (float*)(smem + 32 * 132 * 4);   // [32][36]
        for (int t = bid; t < NN / 32; t += Glin) {
            const int row0 = t * 32;
            const int d4 = tid & 31;
            const int rg = tid >> 5;
            float acc[4][4];
            #pragma unroll
            for (int r = 0; r < 4; ++r)
                #pragma unroll
                for (int c = 0; c < 4; ++c) acc[r][c] = 0.0f;
            for (int kt = 0; kt < 4; ++kt) {
                #pragma unroll
                for (int i = tid; i < 4096; i += 256) {
                    int o = i >> 5, kk = i & 31;
                    Wl[kk * 132 + o] = Wm[(size_t)o * DD + kt * 32 + kk];
                }
                #pragma unroll
                for (int i = tid; i < 1024; i += 256) {
                    int r = i >> 5, kk = i & 31;
                    xl[kk * 36 + r] = x[(size_t)(row0 + r) * DD + kt * 32 + kk];
                }
                __syncthreads();
                #pragma unroll 8
                for (int kk = 0; kk < 32; ++kk) {
                    const float4 w4 = *(const float4*)&Wl[kk * 132 + d4 * 4];
                    const float4 x4 = *(const float4*)&xl[kk * 36 + rg * 4];
                    acc[0][0] += x4.x * w4.x; acc[0][1] += x4.x * w4.y; acc[0][2] += x4.x * w4.z; acc[0][3] += x4.x * w4.w;
                    acc[1][0] += x4.y * w4.x; acc[1][1] += x4.y * w4.y; acc[1][2] += x4.y * w4.z; acc[1][3] += x4.y * w4.w;
                    acc[2][0] += x4.z * w4.x; acc[2][1] += x4.z * w4.y; acc[2][2] += x4.z * w4.z; acc[2][3] += x4.z * w4.w;
                    acc[3][0] += x4.w * w4.x; acc[3][1] += x4.w * w4.y; acc[3][2] += x4.w * w4.z; acc[3][3] += x4.w * w4.w;
                }
                __syncthreads();
            }
            const float4 b4 = *(const float4*)&bias[d4 * 4];
            #pragma unroll
            for (int r = 0; r < 4; ++r) {
                const int row = row0 + rg * 4 + r;
                float4 o;
                o.x = acc[r][0] + b4.x;
                o.y = acc[r][1] + b4.y;
                o.z = acc[r][2] + b4.z;
                o.w = acc[r][3] + b4.w;
                *(float4*)&h[(size_t)row * DD + d4 * 4] = o;
            }
        }
    } else {
        const int sid = bid - Glin;
        const int NS = G - Glin;
        for (int e = sid * 256 + tid; e < E; e += NS * 256) {
            int src = ei[e];
            int dst = ei[E + e];
            if ((unsigned)src < (unsigned)NN && (unsigned)dst < (unsigned)NN) {
                int pos = atomicAdd(&cnt[src], 1);
                if (pos < RCAP) adj[(size_t)src * RCAP + pos] = dst;
            }
        }
    }
    grid.sync();

    // ---------------- C: per-row LDS-bitmap dedup -> sorted unique list + ucnt
    {
        unsigned* bm = (unsigned*)smem;           // 256 words = 1 KB row bitmap
        int* wbase = (int*)(smem + 1024);         // [4]
        const int lane = tid & 63;
        const int wave = tid >> 6;
        for (int row = bid; row < NN; row += G) {
            bm[tid] = 0u;
            __syncthreads();
            int rc = cnt[row]; if (rc > RCAP) rc = RCAP;
            for (int k = tid; k < rc; k += 256) {
                int dst = adj[(size_t)row * RCAP + k];
                atomicOr(&bm[dst >> 5], 1u << (dst & 31));
            }
            __syncthreads();
            unsigned w = bm[wave * 64 + lane];
            int c = __popc(w);
            int scan = c;
            #pragma unroll
            for (int off = 1; off < 64; off <<= 1) {
                int o = __shfl_up(scan, off);
                if (lane >= off) scan += o;
            }
            if (lane == 63) wbase[wave] = scan;
            __syncthreads();
            int base = scan - c;
            #pragma unroll
            for (int q = 0; q < 4; ++q) if (q < wave) base += wbase[q];
            const int b0 = (wave * 64 + lane) * 32;
            while (w) {
                int b = __ffs(w) - 1;
                w &= w - 1;
                uadj[(size_t)row * RCAP + base++] = b0 + b;
            }
            if (tid == 0) ucnt[row] = wbase[0] + wbase[1] + wbase[2] + wbase[3];
            __syncthreads();
        }
    }
    grid.sync();

    // ---------------- D: out[i] = dinv_i * ( dinv_i*h_i + sum_j dinv_j*h_j )
    {
        float4* red = (float4*)smem;              // [8][32] = 4 KB
        int* nl = (int*)(smem + 4096);            // [RCAP]
        float* nd = (float*)(smem + 4096 + RCAP * 4);
        const int sub = tid >> 5;
        const int d4 = tid & 31;
        const float4* h4 = (const float4*)h;
        for (int row = bid; row < NN; row += G) {
            const int u = ucnt[row];
            for (int k = tid; k < u; k += 256) {
                int j = uadj[(size_t)row * RCAP + k];
                nl[k] = j;
                nd[k] = rsqrtf((float)(ucnt[j] + 1));
            }
            __syncthreads();
            float4 a0 = make_float4(0.f, 0.f, 0.f, 0.f);
            float4 a1 = make_float4(0.f, 0.f, 0.f, 0.f);
            int k = sub;
            for (; k + 8 < u; k += 16) {
                int j0 = nl[k];     float s0 = nd[k];
                int j1 = nl[k + 8]; float s1 = nd[k + 8];
                float4 v0 = h4[(size_t)j0 * 32 + d4];
                float4 v1 = h4[(size_t)j1 * 32 + d4];
                a0.x += s0 * v0.x; a0.y += s0 * v0.y; a0.z += s0 * v0.z; a0.w += s0 * v0.w;
                a1.x += s1 * v1.x; a1.y += s1 * v1.y; a1.z += s1 * v1.z; a1.w += s1 * v1.w;
            }
            if (k < u) {
                float s0 = nd[k];
                float4 v0 = h4[(size_t)nl[k] * 32 + d4];
                a0.x += s0 * v0.x; a0.y += s0 * v0.y; a0.z += s0 * v0.z; a0.w += s0 * v0.w;
            }
            a0.x += a1.x; a0.y += a1.y; a0.z += a1.z; a0.w += a1.w;
            red[sub * 32 + d4] = a0;
            __syncthreads();
            if (tid < 128) {
                const float* redf = (const float*)red;  // [8][128]
                float s = 0.f;
                #pragma unroll
                for (int q = 0; q < 8; ++q) s += redf[q * 128 + tid];
                const float di = rsqrtf((float)(u + 1));
                s += di * h[(size_t)row * DD + tid];    // eye self-term
                out[(size_t)row * DD + tid] = di * s;
            }
            __syncthreads();
        }
    }
}

// ============================================================================
// FALLBACK path (round-6, proven): used only if cooperative launch is refused
// ============================================================================
__global__ __launch_bounds__(256) void zero_kernel(uint4* __restrict__ p, int n4) {
    int i = blockIdx.x * blockDim.x + threadIdx.x;
    if (i < n4) p[i] = make_uint4(0u, 0u, 0u, 0u);
}

__global__ __launch_bounds__(256) void edge_pass1(const int* __restrict__ ei, int E,
                                                  unsigned int* __restrict__ bitmap,
                                                  int* __restrict__ counts) {
    int e = blockIdx.x * blockDim.x + threadIdx.x;
    if (e >= E) return;
    int src = ei[e];
    int dst = ei[E + e];
    if ((unsigned)src < (unsigned)NN && (unsigned)dst < (unsigned)NN) {
        unsigned mask = 1u << (dst & 31);
        unsigned old = atomicOr(&bitmap[(size_t)src * WPR + (dst >> 5)], mask);
        if (!(old & mask)) atomicAdd(&counts[src], 1);
    }
}

__global__ __launch_bounds__(64) void linear_kernel(const float* __restrict__ x,
                                                    const float* __restrict__ Wm,
                                                    const float* __restrict__ bias,
                                                    const int* __restrict__ counts,
                                                    float* __restrict__ g) {
    __shared__ float Wl[32][36];
    __shared__ float xl[32][36];
    const int tid = threadIdx.x;
    const int row0 = (blockIdx.x >> 2) * 32;
    const int c0   = (blockIdx.x & 3) * 32;
    const int d4 = tid & 7;
    const int rg = tid >> 3;

    float acc[4][4];
    #pragma unroll
    for (int r = 0; r < 4; ++r)
        #pragma unroll
        for (int c = 0; c < 4; ++c) acc[r][c] = 0.0f;

    for (int kt = 0; kt < 4; ++kt) {
        #pragma unroll
        for (int i = tid; i < 1024; i += 64) {
            int o = i >> 5, kk = i & 31;
            Wl[kk][o] = Wm[(size_t)(c0 + o) * DD + kt * 32 + kk];
        }
        #pragma unroll
        for (int i = tid; i < 1024; i += 64) {
            int r = i >> 5, kk = i & 31;
            xl[kk][r] = x[(size_t)(row0 + r) * DD + kt * 32 + kk];
        }
        __syncthreads();
        #pragma unroll 8
        for (int kk = 0; kk < 32; ++kk) {
            const float4 w4 = *(const float4*)&Wl[kk][d4 * 4];
            const float4 x4 = *(const float4*)&xl[kk][rg * 4];
            acc[0][0] += x4.x * w4.x; acc[0][1] += x4.x * w4.y; acc[0][2] += x4.x * w4.z; acc[0][3] += x4.x * w4.w;
            acc[1][0] += x4.y * w4.x; acc[1][1] += x4.y * w4.y; acc[1][2] += x4.y * w4.z; acc[1][3] += x4.y * w4.w;
            acc[2][0] += x4.z * w4.x; acc[2][1] += x4.z * w4.y; acc[2][2] += x4.z * w4.z; acc[2][3] += x4.z * w4.w;
            acc[3][0] += x4.w * w4.x; acc[3][1] += x4.w * w4.y; acc[3][2] += x4.w * w4.z; acc[3][3] += x4.w * w4.w;
        }
        __syncthreads();
    }

    const float4 b4 = *(const float4*)&bias[c0 + d4 * 4];
    #pragma unroll
    for (int r = 0; r < 4; ++r) {
        const int row = row0 + rg * 4 + r;
        const float dv = rsqrtf((float)(counts[row] + 1));
        float4 o;
        o.x = (acc[r][0] + b4.x) * dv;
        o.y = (acc[r][1] + b4.y) * dv;
        o.z = (acc[r][2] + b4.z) * dv;
        o.w = (acc[r][3] + b4.w) * dv;
        *(float4*)&g[(size_t)row * DD + c0 + d4 * 4] = o;
    }
}

#define FCAP 512
__global__ __launch_bounds__(256) void agg_kernel(const unsigned int* __restrict__ bitmap,
                                                  const int* __restrict__ counts,
                                                  const float* __restrict__ g,
                                                  float* __restrict__ out) {
    __shared__ int nbr[4][FCAP];
    __shared__ int cntl[4];
    __shared__ float4 red[8][32];
    const int i = blockIdx.x;
    const int tid = threadIdx.x;
    const int lane = tid & 63;
    const int wave = tid >> 6;

    {
        unsigned w = bitmap[(size_t)i * WPR + wave * 64 + lane];
        int c = __popc(w);
        int scan = c;
        #pragma unroll
        for (int off = 1; off < 64; off <<= 1) {
            int o = __shfl_up(scan, off);
            if (lane >= off) scan += o;
        }
        int base = scan - c;
        const int b0 = (wave * 64 + lane) * 32;
        while (w) {
            int b = __ffs(w) - 1;
            w &= w - 1;
            nbr[wave][base++] = b0 + b;
        }
        if (lane == 63) cntl[wave] = scan;
    }
    __syncthreads();

    const int sub = tid >> 5;
    const int d4 = tid & 31;
    const float4* g4 = (const float4*)g;
    float4 a0 = make_float4(0.f, 0.f, 0.f, 0.f);
    float4 a1 = make_float4(0.f, 0.f, 0.f, 0.f);
    #pragma unroll
    for (int q = 0; q < 4; ++q) {
        const int n = cntl[q];
        const int* lst = nbr[q];
        int k = sub;
        for (; k + 8 < n; k += 16) {
            int j0 = lst[k];
            int j1 = lst[k + 8];
            float4 v0 = g4[(size_t)j0 * 32 + d4];
            float4 v1 = g4[(size_t)j1 * 32 + d4];
            a0.x += v0.x; a0.y += v0.y; a0.z += v0.z; a0.w += v0.w;
            a1.x += v1.x; a1.y += v1.y; a1.z += v1.z; a1.w += v1.w;
        }
        if (k < n) {
            float4 v0 = g4[(size_t)lst[k] * 32 + d4];
            a0.x += v0.x; a0.y += v0.y; a0.z += v0.z; a0.w += v0.w;
        }
    }
    a0.x += a1.x; a0.y += a1.y; a0.z += a1.z; a0.w += a1.w;
    red[sub][d4] = a0;
    __syncthreads();

    if (tid < 128) {
        const float* redf = (const float*)red;
        float s = 0.f;
        #pragma unroll
        for (int q = 0; q < 8; ++q) s += redf[q * 128 + tid];
        s += g[(size_t)i * DD + tid];
        const float di = rsqrtf((float)(counts[i] + 1));
        out[(size_t)i * DD + tid] = di * s;
    }
}

// ============================================================================
extern "C" void kernel_launch(void* const* d_in, const int* in_sizes, int n_in,
                              void* d_out, int out_size, void* d_ws, size_t ws_size,
                              hipStream_t stream) {
    const float* x  = (const float*)d_in[0];
    const int*   ei = (const int*)d_in[1];
    const float* Wm = (const float*)d_in[2];
    const float* bs = (const float*)d_in[3];
    float* out = (float*)d_out;
    const int E = in_sizes[1] / 2;

    // fused-path workspace (~10.1 MB)
    char* p = (char*)d_ws;
    int* cnt  = (int*)p;   p += (size_t)NN * sizeof(int);
    int* ucnt = (int*)p;   p += (size_t)NN * sizeof(int);
    int* adj  = (int*)p;   p += (size_t)NN * RCAP * sizeof(int);   // 3 MB
    int* uadj = (int*)p;   p += (size_t)NN * RCAP * sizeof(int);   // 3 MB
    float* h  = (float*)p;                                          // 4 MB

    int occ = 0;
    hipError_t qe = hipOccupancyMaxActiveBlocksPerMultiprocessor(
        &occ, (const void*)fused_kernel, 256, 0);
    int G = (qe == hipSuccess && occ > 0) ? occ * 256 : 512;
    if (G > 1024) G = 1024;
    if (G < 8)    G = 8;

    void* args[] = {(void*)&x, (void*)&ei, (void*)&Wm, (void*)&bs, (void*)&out,
                    (void*)&cnt, (void*)&ucnt, (void*)&adj, (void*)&uadj,
                    (void*)&h, (void*)&E};
    hipError_t le = hipLaunchCooperativeKernel((const void*)fused_kernel,
                                               dim3(G), dim3(256), args, 0, stream);
    if (le != hipSuccess) {
        // ---------- fallback: proven round-6 pipeline at a disjoint ws offset
        char* q = (char*)d_ws + (64u << 20);
        unsigned int* bitmap = (unsigned int*)q;  q += (size_t)NN * WPR * sizeof(unsigned);
        int* counts = (int*)q;                    q += (size_t)NN * sizeof(int);
        float* g    = (float*)q;

        const int zero_bytes = (int)((size_t)NN * WPR * sizeof(unsigned) + (size_t)NN * sizeof(int));
        const int n4 = zero_bytes / 16;
        zero_kernel<<<(n4 + 255) / 256, 256, 0, stream>>>((uint4*)bitmap, n4);
        edge_pass1<<<(E + 255) / 256, 256, 0, stream>>>(ei, E, bitmap, counts);
        linear_kernel<<<1024, 64, 0, stream>>>(x, Wm, bs, counts, g);
        agg_kernel<<<NN, 256, 0, stream>>>(bitmap, counts, g, out);
    }
}

// Round 9
// 55.749 us; speedup vs baseline: 4.4602x; 4.4602x over previous
//
#include <hip/hip_runtime.h>
#include <cstdint>
#include <cstddef>

#define NN 8192          // nodes
#define DD 128           // feature dim (in == out)
#define RCAP 96          // raw per-row CSR capacity (Binomial(262144,1/8192): mean 32, max ~60)

// ------------------------------------------------ zero cnt[NN] (32 KB)
__global__ __launch_bounds__(256) void zero_kernel(uint4* __restrict__ p, int n4) {
    int i = blockIdx.x * blockDim.x + threadIdx.x;
    if (i < n4) p[i] = make_uint4(0u, 0u, 0u, 0u);
}

// ------------------------------------------------ edges -> raw per-row CSR
__global__ __launch_bounds__(256) void scatter_kernel(const int* __restrict__ ei, int E,
                                                      int* __restrict__ cnt,
                                                      int* __restrict__ adj) {
    int e = blockIdx.x * blockDim.x + threadIdx.x;
    if (e >= E) return;
    int src = ei[e];
    int dst = ei[E + e];
    if ((unsigned)src < (unsigned)NN && (unsigned)dst < (unsigned)NN) {
        int pos = atomicAdd(&cnt[src], 1);
        if (pos < RCAP) adj[(size_t)src * RCAP + pos] = dst;
    }
}

// ------------------------------------------------ per-row dedup via LDS bitmap
// 4 rows per 256-thread block (1 wave per row). Scalar LDS accesses + block
// barriers between zero/atomic/read phases (port of round-7's proven phase C).
__global__ __launch_bounds__(256) void dedup_kernel(const int* __restrict__ cnt,
                                                    const int* __restrict__ adj,
                                                    int* __restrict__ uadj,
                                                    int* __restrict__ ucnt) {
    __shared__ unsigned bm[4][256];   // 1 KB bitmap per wave/row
    const int tid = threadIdx.x;
    const int lane = tid & 63;
    const int wave = tid >> 6;
    const int row = blockIdx.x * 4 + wave;

    // zero own wave's bitmap (scalar, 4 words per lane)
    bm[wave][lane]       = 0u;
    bm[wave][lane + 64]  = 0u;
    bm[wave][lane + 128] = 0u;
    bm[wave][lane + 192] = 0u;
    __syncthreads();

    int rc = cnt[row]; if (rc > RCAP) rc = RCAP;
    for (int k = lane; k < rc; k += 64) {
        int dst = adj[(size_t)row * RCAP + k];
        atomicOr(&bm[wave][dst >> 5], 1u << (dst & 31));
    }
    __syncthreads();

    // scalar reads of this lane's 4 words (bits [lane*128, lane*128+127])
    unsigned w0 = bm[wave][lane * 4 + 0];
    unsigned w1 = bm[wave][lane * 4 + 1];
    unsigned w2 = bm[wave][lane * 4 + 2];
    unsigned w3 = bm[wave][lane * 4 + 3];
    int c = __popc(w0) + __popc(w1) + __popc(w2) + __popc(w3);
    int scan = c;
    #pragma unroll
    for (int off = 1; off < 64; off <<= 1) {
        int o = __shfl_up(scan, off);
        if (lane >= off) scan += o;
    }
    int pos = row * RCAP + (scan - c);
    const int b0 = lane * 128;
    unsigned ws[4] = {w0, w1, w2, w3};
    #pragma unroll
    for (int q = 0; q < 4; ++q) {
        unsigned w = ws[q];
        while (w) {
            int bb = __ffs(w) - 1;
            w &= w - 1;
            uadj[pos++] = b0 + q * 32 + bb;
        }
    }
    if (lane == 63) ucnt[row] = scan;
}

// ------------------------------------------------ g = dinv[row] * (x @ W^T + b)
// 1-wave blocks, 32 rows x 32 cols per block; 4x4 per-thread micro-tile.
__global__ __launch_bounds__(64) void linear_kernel(const float* __restrict__ x,
                                                    const float* __restrict__ Wm,
                                                    const float* __restrict__ bias,
                                                    const int* __restrict__ ucnt,
                                                    float* __restrict__ g) {
    __shared__ float Wl[32][36];  // [kk][o]
    __shared__ float xl[32][36];  // [kk][r]
    const int tid = threadIdx.x;
    const int row0 = (blockIdx.x >> 2) * 32;
    const int c0   = (blockIdx.x & 3) * 32;
    const int d4 = tid & 7;
    const int rg = tid >> 3;

    float acc[4][4];
    #pragma unroll
    for (int r = 0; r < 4; ++r)
        #pragma unroll
        for (int c = 0; c < 4; ++c) acc[r][c] = 0.0f;

    for (int kt = 0; kt < 4; ++kt) {
        #pragma unroll
        for (int i = tid; i < 1024; i += 64) {
            int o = i >> 5, kk = i & 31;
            Wl[kk][o] = Wm[(size_t)(c0 + o) * DD + kt * 32 + kk];
        }
        #pragma unroll
        for (int i = tid; i < 1024; i += 64) {
            int r = i >> 5, kk = i & 31;
            xl[kk][r] = x[(size_t)(row0 + r) * DD + kt * 32 + kk];
        }
        __syncthreads();
        #pragma unroll 8
        for (int kk = 0; kk < 32; ++kk) {
            const float4 w4 = *(const float4*)&Wl[kk][d4 * 4];
            const float4 x4 = *(const float4*)&xl[kk][rg * 4];
            acc[0][0] += x4.x * w4.x; acc[0][1] += x4.x * w4.y; acc[0][2] += x4.x * w4.z; acc[0][3] += x4.x * w4.w;
            acc[1][0] += x4.y * w4.x; acc[1][1] += x4.y * w4.y; acc[1][2] += x4.y * w4.z; acc[1][3] += x4.y * w4.w;
            acc[2][0] += x4.z * w4.x; acc[2][1] += x4.z * w4.y; acc[2][2] += x4.z * w4.z; acc[2][3] += x4.z * w4.w;
            acc[3][0] += x4.w * w4.x; acc[3][1] += x4.w * w4.y; acc[3][2] += x4.w * w4.z; acc[3][3] += x4.w * w4.w;
        }
        __syncthreads();
    }

    const float4 b4 = *(const float4*)&bias[c0 + d4 * 4];
    #pragma unroll
    for (int r = 0; r < 4; ++r) {
        const int row = row0 + rg * 4 + r;
        const float dv = rsqrtf((float)(ucnt[row] + 1));
        float4 o;
        o.x = (acc[r][0] + b4.x) * dv;
        o.y = (acc[r][1] + b4.y) * dv;
        o.z = (acc[r][2] + b4.z) * dv;
        o.w = (acc[r][3] + b4.w) * dv;
        *(float4*)&g[(size_t)row * DD + c0 + d4 * 4] = o;
    }
}

// ------------------------------------------------ out[i] = dinv[i]*(g[i] + sum_{j in uadj(i)} g[j])
__global__ __launch_bounds__(256) void agg_kernel(const int* __restrict__ ucnt,
                                                  const int* __restrict__ uadj,
                                                  const float* __restrict__ g,
                                                  float* __restrict__ out) {
    __shared__ int nl[RCAP];
    __shared__ float4 red[8][32];
    const int i = blockIdx.x;
    const int tid = threadIdx.x;
    const int u = ucnt[i];
    if (tid < u) nl[tid] = uadj[(size_t)i * RCAP + tid];   // u <= 96 < 256
    __syncthreads();

    const int sub = tid >> 5;
    const int d4 = tid & 31;
    const float4* g4 = (const float4*)g;
    float4 a0 = make_float4(0.f, 0.f, 0.f, 0.f);
    float4 a1 = make_float4(0.f, 0.f, 0.f, 0.f);
    int k = sub;
    for (; k + 8 < u; k += 16) {
        int j0 = nl[k];
        int j1 = nl[k + 8];
        float4 v0 = g4[(size_t)j0 * 32 + d4];
        float4 v1 = g4[(size_t)j1 * 32 + d4];
        a0.x += v0.x; a0.y += v0.y; a0.z += v0.z; a0.w += v0.w;
        a1.x += v1.x; a1.y += v1.y; a1.z += v1.z; a1.w += v1.w;
    }
    if (k < u) {
        float4 v0 = g4[(size_t)nl[k] * 32 + d4];
        a0.x += v0.x; a0.y += v0.y; a0.z += v0.z; a0.w += v0.w;
    }
    a0.x += a1.x; a0.y += a1.y; a0.z += a1.z; a0.w += a1.w;
    red[sub][d4] = a0;
    __syncthreads();

    if (tid < 128) {
        const float* redf = (const float*)red;  // [8][128]
        float s = 0.f;
        #pragma unroll
        for (int q = 0; q < 8; ++q) s += redf[q * 128 + tid];
        s += g[(size_t)i * DD + tid];           // eye self-term (g already dinv-scaled)
        const float di = rsqrtf((float)(u + 1));
        out[(size_t)i * DD + tid] = di * s;
    }
}

extern "C" void kernel_launch(void* const* d_in, const int* in_sizes, int n_in,
                              void* d_out, int out_size, void* d_ws, size_t ws_size,
                              hipStream_t stream) {
    const float* x  = (const float*)d_in[0];
    const int*   ei = (const int*)d_in[1];
    const float* Wm = (const float*)d_in[2];
    const float* bs = (const float*)d_in[3];
    float* out = (float*)d_out;
    const int E = in_sizes[1] / 2;

    // workspace (~10.2 MB)
    char* p = (char*)d_ws;
    int* cnt  = (int*)p;   p += (size_t)NN * sizeof(int);            // 32 KB
    int* ucnt = (int*)p;   p += (size_t)NN * sizeof(int);            // 32 KB
    int* adj  = (int*)p;   p += (size_t)NN * RCAP * sizeof(int);     // 3 MB
    int* uadj = (int*)p;   p += (size_t)NN * RCAP * sizeof(int);     // 3 MB
    float* g  = (float*)p;                                           // 4 MB

    const int n4 = (NN * (int)sizeof(int)) / 16;   // cnt only
    zero_kernel<<<(n4 + 255) / 256, 256, 0, stream>>>((uint4*)cnt, n4);
    scatter_kernel<<<(E + 255) / 256, 256, 0, stream>>>(ei, E, cnt, adj);
    dedup_kernel<<<NN / 4, 256, 0, stream>>>(cnt, adj, uadj, ucnt);
    linear_kernel<<<1024, 64, 0, stream>>>(x, Wm, bs, ucnt, g);
    agg_kernel<<<NN, 256, 0, stream>>>(ucnt, uadj, g, out);
}

// Round 10
// 53.477 us; speedup vs baseline: 4.6497x; 1.0425x over previous
//
#include <hip/hip_runtime.h>
#include <cstdint>
#include <cstddef>

#define NN 8192          // nodes
#define DD 128           // feature dim (in == out)
#define RCAP 96          // raw per-row CSR capacity (Binomial(262144,1/8192): mean 32, max ~60)

// ------------------------------------------------ edges -> raw per-row CSR
__global__ __launch_bounds__(256) void scatter_kernel(const int* __restrict__ ei, int E,
                                                      int* __restrict__ cnt,
                                                      int* __restrict__ adj) {
    int e = blockIdx.x * blockDim.x + threadIdx.x;
    if (e >= E) return;
    int src = ei[e];
    int dst = ei[E + e];
    if ((unsigned)src < (unsigned)NN && (unsigned)dst < (unsigned)NN) {
        int pos = atomicAdd(&cnt[src], 1);
        if (pos < RCAP) adj[(size_t)src * RCAP + pos] = dst;
    }
}

// ------------------------------------------------ per-row dedup via LDS bitmap
// 4 rows per 256-thread block (1 wave per row). Scalar LDS + block barriers
// (round-9 proven). Emits sorted uadj, ucnt, and dinv = rsqrt(ucnt+1).
__global__ __launch_bounds__(256) void dedup_kernel(const int* __restrict__ cnt,
                                                    const int* __restrict__ adj,
                                                    int* __restrict__ uadj,
                                                    int* __restrict__ ucnt,
                                                    float* __restrict__ dinv) {
    __shared__ unsigned bm[4][256];   // 1 KB bitmap per wave/row
    const int tid = threadIdx.x;
    const int lane = tid & 63;
    const int wave = tid >> 6;
    const int row = blockIdx.x * 4 + wave;

    bm[wave][lane]       = 0u;
    bm[wave][lane + 64]  = 0u;
    bm[wave][lane + 128] = 0u;
    bm[wave][lane + 192] = 0u;
    __syncthreads();

    int rc = cnt[row]; if (rc > RCAP) rc = RCAP;
    for (int k = lane; k < rc; k += 64) {
        int dst = adj[(size_t)row * RCAP + k];
        atomicOr(&bm[wave][dst >> 5], 1u << (dst & 31));
    }
    __syncthreads();

    unsigned w0 = bm[wave][lane * 4 + 0];
    unsigned w1 = bm[wave][lane * 4 + 1];
    unsigned w2 = bm[wave][lane * 4 + 2];
    unsigned w3 = bm[wave][lane * 4 + 3];
    int c = __popc(w0) + __popc(w1) + __popc(w2) + __popc(w3);
    int scan = c;
    #pragma unroll
    for (int off = 1; off < 64; off <<= 1) {
        int o = __shfl_up(scan, off);
        if (lane >= off) scan += o;
    }
    int pos = row * RCAP + (scan - c);
    const int b0 = lane * 128;
    unsigned ws[4] = {w0, w1, w2, w3};
    #pragma unroll
    for (int q = 0; q < 4; ++q) {
        unsigned w = ws[q];
        while (w) {
            int bb = __ffs(w) - 1;
            w &= w - 1;
            uadj[pos++] = b0 + q * 32 + bb;
        }
    }
    if (lane == 63) {
        ucnt[row] = scan;
        dinv[row] = rsqrtf((float)(scan + 1));
    }
}

// ------------------------------------------------ h = x @ W^T + b   (+ zero cnt in first blocks)
// 1-wave blocks, 32 rows x 32 cols per block; 4x4 per-thread micro-tile.
__global__ __launch_bounds__(64) void linear_kernel(const float* __restrict__ x,
                                                    const float* __restrict__ Wm,
                                                    const float* __restrict__ bias,
                                                    int* __restrict__ cnt,
                                                    float* __restrict__ h) {
    // fold the 32KB cnt zero into this kernel (runs before scatter on the stream)
    if (blockIdx.x < 128) cnt[blockIdx.x * 64 + threadIdx.x] = 0;

    __shared__ float Wl[32][36];  // [kk][o]
    __shared__ float xl[32][36];  // [kk][r]
    const int tid = threadIdx.x;
    const int row0 = (blockIdx.x >> 2) * 32;
    const int c0   = (blockIdx.x & 3) * 32;
    const int d4 = tid & 7;
    const int rg = tid >> 3;

    float acc[4][4];
    #pragma unroll
    for (int r = 0; r < 4; ++r)
        #pragma unroll
        for (int c = 0; c < 4; ++c) acc[r][c] = 0.0f;

    for (int kt = 0; kt < 4; ++kt) {
        #pragma unroll
        for (int i = tid; i < 1024; i += 64) {
            int o = i >> 5, kk = i & 31;
            Wl[kk][o] = Wm[(size_t)(c0 + o) * DD + kt * 32 + kk];
        }
        #pragma unroll
        for (int i = tid; i < 1024; i += 64) {
            int r = i >> 5, kk = i & 31;
            xl[kk][r] = x[(size_t)(row0 + r) * DD + kt * 32 + kk];
        }
        __syncthreads();
        #pragma unroll 8
        for (int kk = 0; kk < 32; ++kk) {
            const float4 w4 = *(const float4*)&Wl[kk][d4 * 4];
            const float4 x4 = *(const float4*)&xl[kk][rg * 4];
            acc[0][0] += x4.x * w4.x; acc[0][1] += x4.x * w4.y; acc[0][2] += x4.x * w4.z; acc[0][3] += x4.x * w4.w;
            acc[1][0] += x4.y * w4.x; acc[1][1] += x4.y * w4.y; acc[1][2] += x4.y * w4.z; acc[1][3] += x4.y * w4.w;
            acc[2][0] += x4.z * w4.x; acc[2][1] += x4.z * w4.y; acc[2][2] += x4.z * w4.z; acc[2][3] += x4.z * w4.w;
            acc[3][0] += x4.w * w4.x; acc[3][1] += x4.w * w4.y; acc[3][2] += x4.w * w4.z; acc[3][3] += x4.w * w4.w;
        }
        __syncthreads();
    }

    const float4 b4 = *(const float4*)&bias[c0 + d4 * 4];
    #pragma unroll
    for (int r = 0; r < 4; ++r) {
        const int row = row0 + rg * 4 + r;
        float4 o;
        o.x = acc[r][0] + b4.x;
        o.y = acc[r][1] + b4.y;
        o.z = acc[r][2] + b4.z;
        o.w = acc[r][3] + b4.w;
        *(float4*)&h[(size_t)row * DD + c0 + d4 * 4] = o;
    }
}

// ------------------------------------------------ out[i] = dinv[i]*(dinv[i]*h[i] + sum_j dinv[j]*h[j])
// Block per row: list+dinv to LDS (1 barrier), 8 slices x 32 lanes, 4-deep ILP gather.
__global__ __launch_bounds__(256) void agg_kernel(const int* __restrict__ ucnt,
                                                  const int* __restrict__ uadj,
                                                  const float* __restrict__ dinv,
                                                  const float* __restrict__ h,
                                                  float* __restrict__ out) {
    __shared__ int nl[RCAP];
    __shared__ float nd[RCAP];
    __shared__ float4 red[8][32];
    const int i = blockIdx.x;
    const int tid = threadIdx.x;
    const int u = ucnt[i];
    if (tid < u) {
        int j = uadj[(size_t)i * RCAP + tid];   // u <= 96 < 256
        nl[tid] = j;
        nd[tid] = dinv[j];
    }
    __syncthreads();

    const int sub = tid >> 5;
    const int d4 = tid & 31;
    const float4* h4 = (const float4*)h;
    float4 a0 = make_float4(0.f, 0.f, 0.f, 0.f);
    float4 a1 = make_float4(0.f, 0.f, 0.f, 0.f);
    float4 a2 = make_float4(0.f, 0.f, 0.f, 0.f);
    float4 a3 = make_float4(0.f, 0.f, 0.f, 0.f);
    int k = sub;
    for (; k + 24 < u; k += 32) {
        int j0 = nl[k], j1 = nl[k + 8], j2 = nl[k + 16], j3 = nl[k + 24];
        float s0 = nd[k], s1 = nd[k + 8], s2 = nd[k + 16], s3 = nd[k + 24];
        float4 v0 = h4[(size_t)j0 * 32 + d4];
        float4 v1 = h4[(size_t)j1 * 32 + d4];
        float4 v2 = h4[(size_t)j2 * 32 + d4];
        float4 v3 = h4[(size_t)j3 * 32 + d4];
        a0.x += s0 * v0.x; a0.y += s0 * v0.y; a0.z += s0 * v0.z; a0.w += s0 * v0.w;
        a1.x += s1 * v1.x; a1.y += s1 * v1.y; a1.z += s1 * v1.z; a1.w += s1 * v1.w;
        a2.x += s2 * v2.x; a2.y += s2 * v2.y; a2.z += s2 * v2.z; a2.w += s2 * v2.w;
        a3.x += s3 * v3.x; a3.y += s3 * v3.y; a3.z += s3 * v3.z; a3.w += s3 * v3.w;
    }
    for (; k < u; k += 8) {
        float s0 = nd[k];
        float4 v0 = h4[(size_t)nl[k] * 32 + d4];
        a0.x += s0 * v0.x; a0.y += s0 * v0.y; a0.z += s0 * v0.z; a0.w += s0 * v0.w;
    }
    a0.x += a1.x + a2.x + a3.x;
    a0.y += a1.y + a2.y + a3.y;
    a0.z += a1.z + a2.z + a3.z;
    a0.w += a1.w + a2.w + a3.w;
    red[sub][d4] = a0;
    __syncthreads();

    if (tid < 128) {
        const float* redf = (const float*)red;  // [8][128]
        float s = 0.f;
        #pragma unroll
        for (int q = 0; q < 8; ++q) s += redf[q * 128 + tid];
        const float di = dinv[i];
        const float hv = h[(size_t)i * DD + tid];
        out[(size_t)i * DD + tid] = di * (s + di * hv);   // eye self-term
    }
}

extern "C" void kernel_launch(void* const* d_in, const int* in_sizes, int n_in,
                              void* d_out, int out_size, void* d_ws, size_t ws_size,
                              hipStream_t stream) {
    const float* x  = (const float*)d_in[0];
    const int*   ei = (const int*)d_in[1];
    const float* Wm = (const float*)d_in[2];
    const float* bs = (const float*)d_in[3];
    float* out = (float*)d_out;
    const int E = in_sizes[1] / 2;

    // workspace (~10.2 MB)
    char* p = (char*)d_ws;
    int* cnt   = (int*)p;   p += (size_t)NN * sizeof(int);            // 32 KB
    int* ucnt  = (int*)p;   p += (size_t)NN * sizeof(int);            // 32 KB
    float* dinv = (float*)p; p += (size_t)NN * sizeof(float);         // 32 KB
    int* adj   = (int*)p;   p += (size_t)NN * RCAP * sizeof(int);     // 3 MB
    int* uadj  = (int*)p;   p += (size_t)NN * RCAP * sizeof(int);     // 3 MB
    float* h   = (float*)p;                                           // 4 MB

    linear_kernel<<<1024, 64, 0, stream>>>(x, Wm, bs, cnt, h);        // also zeroes cnt
    scatter_kernel<<<(E + 255) / 256, 256, 0, stream>>>(ei, E, cnt, adj);
    dedup_kernel<<<NN / 4, 256, 0, stream>>>(cnt, adj, uadj, ucnt, dinv);
    agg_kernel<<<NN, 256, 0, stream>>>(ucnt, uadj, dinv, h, out);
}

// Round 11
// 52.813 us; speedup vs baseline: 4.7082x; 1.0126x over previous
//
#include <hip/hip_runtime.h>
#include <hip/hip_fp16.h>
#include <cstdint>
#include <cstddef>

#define NN 8192          // nodes
#define DD 128           // feature dim (in == out)
#define RCAP 96          // raw per-row CSR capacity (Binomial(262144,1/8192): mean 32, max ~60)

// ------------------------------------------------ edges -> raw per-row CSR
__global__ __launch_bounds__(256) void scatter_kernel(const int* __restrict__ ei, int E,
                                                      int* __restrict__ cnt,
                                                      int* __restrict__ adj) {
    int e = blockIdx.x * blockDim.x + threadIdx.x;
    if (e >= E) return;
    int src = ei[e];
    int dst = ei[E + e];
    if ((unsigned)src < (unsigned)NN && (unsigned)dst < (unsigned)NN) {
        int pos = atomicAdd(&cnt[src], 1);
        if (pos < RCAP) adj[(size_t)src * RCAP + pos] = dst;
    }
}

// ------------------------------------------------ per-row dedup via LDS bitmap
// 4 rows per 256-thread block (1 wave per row). Scalar LDS + block barriers
// (round-9 proven). Emits sorted uadj, ucnt, dinv = rsqrt(ucnt+1).
__global__ __launch_bounds__(256) void dedup_kernel(const int* __restrict__ cnt,
                                                    const int* __restrict__ adj,
                                                    int* __restrict__ uadj,
                                                    int* __restrict__ ucnt,
                                                    float* __restrict__ dinv) {
    __shared__ unsigned bm[4][256];   // 1 KB bitmap per wave/row
    const int tid = threadIdx.x;
    const int lane = tid & 63;
    const int wave = tid >> 6;
    const int row = blockIdx.x * 4 + wave;

    bm[wave][lane]       = 0u;
    bm[wave][lane + 64]  = 0u;
    bm[wave][lane + 128] = 0u;
    bm[wave][lane + 192] = 0u;
    __syncthreads();

    int rc = cnt[row]; if (rc > RCAP) rc = RCAP;
    for (int k = lane; k < rc; k += 64) {
        int dst = adj[(size_t)row * RCAP + k];
        atomicOr(&bm[wave][dst >> 5], 1u << (dst & 31));
    }
    __syncthreads();

    unsigned w0 = bm[wave][lane * 4 + 0];
    unsigned w1 = bm[wave][lane * 4 + 1];
    unsigned w2 = bm[wave][lane * 4 + 2];
    unsigned w3 = bm[wave][lane * 4 + 3];
    int c = __popc(w0) + __popc(w1) + __popc(w2) + __popc(w3);
    int scan = c;
    #pragma unroll
    for (int off = 1; off < 64; off <<= 1) {
        int o = __shfl_up(scan, off);
        if (lane >= off) scan += o;
    }
    int pos = row * RCAP + (scan - c);
    const int b0 = lane * 128;
    unsigned ws[4] = {w0, w1, w2, w3};
    #pragma unroll
    for (int q = 0; q < 4; ++q) {
        unsigned w = ws[q];
        while (w) {
            int bb = __ffs(w) - 1;
            w &= w - 1;
            uadj[pos++] = b0 + q * 32 + bb;
        }
    }
    if (lane == 63) {
        ucnt[row] = scan;
        dinv[row] = rsqrtf((float)(scan + 1));
    }
}

// ------------------------------------------------ h = fp16( x @ W^T + b )   (+ zero cnt)
// 1-wave blocks, 32 rows x 32 cols per block; 4x4 per-thread micro-tile.
__global__ __launch_bounds__(64) void linear_kernel(const float* __restrict__ x,
                                                    const float* __restrict__ Wm,
                                                    const float* __restrict__ bias,
                                                    int* __restrict__ cnt,
                                                    __half* __restrict__ h) {
    // fold the 32KB cnt zero into this kernel (runs before scatter on the stream)
    if (blockIdx.x < 128) cnt[blockIdx.x * 64 + threadIdx.x] = 0;

    __shared__ float Wl[32][36];  // [kk][o]
    __shared__ float xl[32][36];  // [kk][r]
    const int tid = threadIdx.x;
    const int row0 = (blockIdx.x >> 2) * 32;
    const int c0   = (blockIdx.x & 3) * 32;
    const int d4 = tid & 7;
    const int rg = tid >> 3;

    float acc[4][4];
    #pragma unroll
    for (int r = 0; r < 4; ++r)
        #pragma unroll
        for (int c = 0; c < 4; ++c) acc[r][c] = 0.0f;

    for (int kt = 0; kt < 4; ++kt) {
        #pragma unroll
        for (int i = tid; i < 1024; i += 64) {
            int o = i >> 5, kk = i & 31;
            Wl[kk][o] = Wm[(size_t)(c0 + o) * DD + kt * 32 + kk];
        }
        #pragma unroll
        for (int i = tid; i < 1024; i += 64) {
            int r = i >> 5, kk = i & 31;
            xl[kk][r] = x[(size_t)(row0 + r) * DD + kt * 32 + kk];
        }
        __syncthreads();
        #pragma unroll 8
        for (int kk = 0; kk < 32; ++kk) {
            const float4 w4 = *(const float4*)&Wl[kk][d4 * 4];
            const float4 x4 = *(const float4*)&xl[kk][rg * 4];
            acc[0][0] += x4.x * w4.x; acc[0][1] += x4.x * w4.y; acc[0][2] += x4.x * w4.z; acc[0][3] += x4.x * w4.w;
            acc[1][0] += x4.y * w4.x; acc[1][1] += x4.y * w4.y; acc[1][2] += x4.y * w4.z; acc[1][3] += x4.y * w4.w;
            acc[2][0] += x4.z * w4.x; acc[2][1] += x4.z * w4.y; acc[2][2] += x4.z * w4.z; acc[2][3] += x4.z * w4.w;
            acc[3][0] += x4.w * w4.x; acc[3][1] += x4.w * w4.y; acc[3][2] += x4.w * w4.z; acc[3][3] += x4.w * w4.w;
        }
        __syncthreads();
    }

    const float4 b4 = *(const float4*)&bias[c0 + d4 * 4];
    #pragma unroll
    for (int r = 0; r < 4; ++r) {
        const int row = row0 + rg * 4 + r;
        float4 o;
        o.x = acc[r][0] + b4.x;
        o.y = acc[r][1] + b4.y;
        o.z = acc[r][2] + b4.z;
        o.w = acc[r][3] + b4.w;
        union { uint2 u; __half2 hh[2]; } pk;
        pk.hh[0] = __floats2half2_rn(o.x, o.y);
        pk.hh[1] = __floats2half2_rn(o.z, o.w);
        *(uint2*)&h[(size_t)row * DD + c0 + d4 * 4] = pk.u;
    }
}

// ------------------------------------------------ out[i] = dinv[i]*(dinv[i]*h[i] + sum_j dinv[j]*h[j])
// Block per row: list+dinv to LDS, 8 slices x 32 lanes, 8B fp16 gathers, 4-deep ILP.
__global__ __launch_bounds__(256) void agg_kernel(const int* __restrict__ ucnt,
                                                  const int* __restrict__ uadj,
                                                  const float* __restrict__ dinv,
                                                  const __half* __restrict__ h,
                                                  float* __restrict__ out) {
    __shared__ int nl[RCAP];
    __shared__ float nd[RCAP];
    __shared__ float4 red[8][32];
    const int i = blockIdx.x;
    const int tid = threadIdx.x;
    const int u = ucnt[i];
    if (tid < u) {
        int j = uadj[(size_t)i * RCAP + tid];   // u <= 96 < 256
        nl[tid] = j;
        nd[tid] = dinv[j];
    }
    __syncthreads();

    const int sub = tid >> 5;
    const int d4 = tid & 31;
    const uint2* hp = (const uint2*)h;   // 8B = 4 halves; row stride = 32 uint2
    float4 a0 = make_float4(0.f, 0.f, 0.f, 0.f);
    float4 a1 = make_float4(0.f, 0.f, 0.f, 0.f);
    float4 a2 = make_float4(0.f, 0.f, 0.f, 0.f);
    float4 a3 = make_float4(0.f, 0.f, 0.f, 0.f);
    int k = sub;
    for (; k + 24 < u; k += 32) {
        int j0 = nl[k], j1 = nl[k + 8], j2 = nl[k + 16], j3 = nl[k + 24];
        float s0 = nd[k], s1 = nd[k + 8], s2 = nd[k + 16], s3 = nd[k + 24];
        union { uint2 uu; __half2 hh[2]; } c0_, c1_, c2_, c3_;
        c0_.uu = hp[(size_t)j0 * 32 + d4];
        c1_.uu = hp[(size_t)j1 * 32 + d4];
        c2_.uu = hp[(size_t)j2 * 32 + d4];
        c3_.uu = hp[(size_t)j3 * 32 + d4];
        float2 f0a = __half22float2(c0_.hh[0]), f0b = __half22float2(c0_.hh[1]);
        float2 f1a = __half22float2(c1_.hh[0]), f1b = __half22float2(c1_.hh[1]);
        float2 f2a = __half22float2(c2_.hh[0]), f2b = __half22float2(c2_.hh[1]);
        float2 f3a = __half22float2(c3_.hh[0]), f3b = __half22float2(c3_.hh[1]);
        a0.x += s0 * f0a.x; a0.y += s0 * f0a.y; a0.z += s0 * f0b.x; a0.w += s0 * f0b.y;
        a1.x += s1 * f1a.x; a1.y += s1 * f1a.y; a1.z += s1 * f1b.x; a1.w += s1 * f1b.y;
        a2.x += s2 * f2a.x; a2.y += s2 * f2a.y; a2.z += s2 * f2b.x; a2.w += s2 * f2b.y;
        a3.x += s3 * f3a.x; a3.y += s3 * f3a.y; a3.z += s3 * f3b.x; a3.w += s3 * f3b.y;
    }
    for (; k < u; k += 8) {
        float s0 = nd[k];
        union { uint2 uu; __half2 hh[2]; } c0_;
        c0_.uu = hp[(size_t)nl[k] * 32 + d4];
        float2 f0a = __half22float2(c0_.hh[0]), f0b = __half22float2(c0_.hh[1]);
        a0.x += s0 * f0a.x; a0.y += s0 * f0a.y; a0.z += s0 * f0b.x; a0.w += s0 * f0b.y;
    }
    a0.x += a1.x + a2.x + a3.x;
    a0.y += a1.y + a2.y + a3.y;
    a0.z += a1.z + a2.z + a3.z;
    a0.w += a1.w + a2.w + a3.w;
    red[sub][d4] = a0;
    __syncthreads();

    if (tid < 128) {
        const float* redf = (const float*)red;  // [8][128]
        float s = 0.f;
        #pragma unroll
        for (int q = 0; q < 8; ++q) s += redf[q * 128 + tid];
        const float di = dinv[i];
        const float hv = __half2float(h[(size_t)i * DD + tid]);
        out[(size_t)i * DD + tid] = di * (s + di * hv);   // eye self-term
    }
}

extern "C" void kernel_launch(void* const* d_in, const int* in_sizes, int n_in,
                              void* d_out, int out_size, void* d_ws, size_t ws_size,
                              hipStream_t stream) {
    const float* x  = (const float*)d_in[0];
    const int*   ei = (const int*)d_in[1];
    const float* Wm = (const float*)d_in[2];
    const float* bs = (const float*)d_in[3];
    float* out = (float*)d_out;
    const int E = in_sizes[1] / 2;

    // workspace (~8.2 MB)
    char* p = (char*)d_ws;
    int* cnt    = (int*)p;   p += (size_t)NN * sizeof(int);           // 32 KB
    int* ucnt   = (int*)p;   p += (size_t)NN * sizeof(int);           // 32 KB
    float* dinv = (float*)p; p += (size_t)NN * sizeof(float);         // 32 KB
    int* adj    = (int*)p;   p += (size_t)NN * RCAP * sizeof(int);    // 3 MB
    int* uadj   = (int*)p;   p += (size_t)NN * RCAP * sizeof(int);    // 3 MB
    __half* h   = (__half*)p;                                         // 2 MB

    linear_kernel<<<1024, 64, 0, stream>>>(x, Wm, bs, cnt, h);        // also zeroes cnt
    scatter_kernel<<<(E + 255) / 256, 256, 0, stream>>>(ei, E, cnt, adj);
    dedup_kernel<<<NN / 4, 256, 0, stream>>>(cnt, adj, uadj, ucnt, dinv);
    agg_kernel<<<NN, 256, 0, stream>>>(ucnt, uadj, dinv, h, out);
}

// Round 12
// 48.776 us; speedup vs baseline: 5.0978x; 1.0828x over previous
//
#include <hip/hip_runtime.h>
#include <hip/hip_fp16.h>
#include <cstdint>
#include <cstddef>

#define NN 8192          // nodes
#define DD 128           // feature dim (in == out)
#define RCAP 96          // raw per-row CSR capacity (Binomial(262144,1/8192): mean 32, max ~60)

// ------------------------------------------------ edges -> raw per-row CSR
__global__ __launch_bounds__(256) void scatter_kernel(const int* __restrict__ ei, int E,
                                                      int* __restrict__ cnt,
                                                      int* __restrict__ adj) {
    int e = blockIdx.x * blockDim.x + threadIdx.x;
    if (e >= E) return;
    int src = ei[e];
    int dst = ei[E + e];
    if ((unsigned)src < (unsigned)NN && (unsigned)dst < (unsigned)NN) {
        int pos = atomicAdd(&cnt[src], 1);
        if (pos < RCAP) adj[(size_t)src * RCAP + pos] = dst;
    }
}

// ------------------------------------------------ per-row dedup via LDS bitmap
// 4 rows per 256-thread block (1 wave per row). Scalar LDS + block barriers
// (round-9 proven). Emits sorted uadj, ucnt, dinv = rsqrt(ucnt+1).
__global__ __launch_bounds__(256) void dedup_kernel(const int* __restrict__ cnt,
                                                    const int* __restrict__ adj,
                                                    int* __restrict__ uadj,
                                                    int* __restrict__ ucnt,
                                                    float* __restrict__ dinv) {
    __shared__ unsigned bm[4][256];   // 1 KB bitmap per wave/row
    const int tid = threadIdx.x;
    const int lane = tid & 63;
    const int wave = tid >> 6;
    const int row = blockIdx.x * 4 + wave;

    bm[wave][lane]       = 0u;
    bm[wave][lane + 64]  = 0u;
    bm[wave][lane + 128] = 0u;
    bm[wave][lane + 192] = 0u;
    __syncthreads();

    int rc = cnt[row]; if (rc > RCAP) rc = RCAP;
    for (int k = lane; k < rc; k += 64) {
        int dst = adj[(size_t)row * RCAP + k];
        atomicOr(&bm[wave][dst >> 5], 1u << (dst & 31));
    }
    __syncthreads();

    unsigned w0 = bm[wave][lane * 4 + 0];
    unsigned w1 = bm[wave][lane * 4 + 1];
    unsigned w2 = bm[wave][lane * 4 + 2];
    unsigned w3 = bm[wave][lane * 4 + 3];
    int c = __popc(w0) + __popc(w1) + __popc(w2) + __popc(w3);
    int scan = c;
    #pragma unroll
    for (int off = 1; off < 64; off <<= 1) {
        int o = __shfl_up(scan, off);
        if (lane >= off) scan += o;
    }
    int pos = row * RCAP + (scan - c);
    const int b0 = lane * 128;
    unsigned ws[4] = {w0, w1, w2, w3};
    #pragma unroll
    for (int q = 0; q < 4; ++q) {
        unsigned w = ws[q];
        while (w) {
            int bb = __ffs(w) - 1;
            w &= w - 1;
            uadj[pos++] = b0 + q * 32 + bb;
        }
    }
    if (lane == 63) {
        ucnt[row] = scan;
        dinv[row] = rsqrtf((float)(scan + 1));
    }
}

// ------------------------------------------------ h = fp16( x @ W^T + b )   (+ zero cnt)
// 1-wave blocks, 32 rows x 32 cols per block; 4x4 per-thread micro-tile.
__global__ __launch_bounds__(64) void linear_kernel(const float* __restrict__ x,
                                                    const float* __restrict__ Wm,
                                                    const float* __restrict__ bias,
                                                    int* __restrict__ cnt,
                                                    __half* __restrict__ h) {
    // fold the 32KB cnt zero into this kernel (runs before scatter on the stream)
    if (blockIdx.x < 128) cnt[blockIdx.x * 64 + threadIdx.x] = 0;

    __shared__ float Wl[32][36];  // [kk][o]
    __shared__ float xl[32][36];  // [kk][r]
    const int tid = threadIdx.x;
    const int row0 = (blockIdx.x >> 2) * 32;
    const int c0   = (blockIdx.x & 3) * 32;
    const int d4 = tid & 7;
    const int rg = tid >> 3;

    float acc[4][4];
    #pragma unroll
    for (int r = 0; r < 4; ++r)
        #pragma unroll
        for (int c = 0; c < 4; ++c) acc[r][c] = 0.0f;

    for (int kt = 0; kt < 4; ++kt) {
        #pragma unroll
        for (int i = tid; i < 1024; i += 64) {
            int o = i >> 5, kk = i & 31;
            Wl[kk][o] = Wm[(size_t)(c0 + o) * DD + kt * 32 + kk];
        }
        #pragma unroll
        for (int i = tid; i < 1024; i += 64) {
            int r = i >> 5, kk = i & 31;
            xl[kk][r] = x[(size_t)(row0 + r) * DD + kt * 32 + kk];
        }
        __syncthreads();
        #pragma unroll 8
        for (int kk = 0; kk < 32; ++kk) {
            const float4 w4 = *(const float4*)&Wl[kk][d4 * 4];
            const float4 x4 = *(const float4*)&xl[kk][rg * 4];
            acc[0][0] += x4.x * w4.x; acc[0][1] += x4.x * w4.y; acc[0][2] += x4.x * w4.z; acc[0][3] += x4.x * w4.w;
            acc[1][0] += x4.y * w4.x; acc[1][1] += x4.y * w4.y; acc[1][2] += x4.y * w4.z; acc[1][3] += x4.y * w4.w;
            acc[2][0] += x4.z * w4.x; acc[2][1] += x4.z * w4.y; acc[2][2] += x4.z * w4.z; acc[2][3] += x4.z * w4.w;
            acc[3][0] += x4.w * w4.x; acc[3][1] += x4.w * w4.y; acc[3][2] += x4.w * w4.z; acc[3][3] += x4.w * w4.w;
        }
        __syncthreads();
    }

    const float4 b4 = *(const float4*)&bias[c0 + d4 * 4];
    #pragma unroll
    for (int r = 0; r < 4; ++r) {
        const int row = row0 + rg * 4 + r;
        float4 o;
        o.x = acc[r][0] + b4.x;
        o.y = acc[r][1] + b4.y;
        o.z = acc[r][2] + b4.z;
        o.w = acc[r][3] + b4.w;
        union { uint2 u; __half2 hh[2]; } pk;
        pk.hh[0] = __floats2half2_rn(o.x, o.y);
        pk.hh[1] = __floats2half2_rn(o.z, o.w);
        *(uint2*)&h[(size_t)row * DD + c0 + d4 * 4] = pk.u;
    }
}

// ------------------------------------------------ out[i] = dinv[i]*(dinv[i]*h[i] + sum_j dinv[j]*h[j])
// ONE WAVE PER ROW: no barriers, no LDS. Lane owns dims {2*lane, 2*lane+1}.
// Neighbor ids/weights lane-distributed in regs; wave-uniform broadcast via __shfl.
__global__ __launch_bounds__(256) void agg_kernel(const int* __restrict__ ucnt,
                                                  const int* __restrict__ uadj,
                                                  const float* __restrict__ dinv,
                                                  const __half* __restrict__ h,
                                                  float* __restrict__ out) {
    const int lane = threadIdx.x & 63;
    const int wave = threadIdx.x >> 6;
    const int row = blockIdx.x * 4 + wave;
    const int u = ucnt[row];

    int nl0 = 0, nl1 = 0;
    float nd0 = 0.f, nd1 = 0.f;
    if (lane < u) { nl0 = uadj[(size_t)row * RCAP + lane]; nd0 = dinv[nl0]; }
    const int u1 = u - 64;
    if (lane < u1) { nl1 = uadj[(size_t)row * RCAP + 64 + lane]; nd1 = dinv[nl1]; }

    const __half2* h2 = (const __half2*)h;   // row stride = 64 half2
    float2 a0 = make_float2(0.f, 0.f);
    float2 a1 = make_float2(0.f, 0.f);
    float2 a2 = make_float2(0.f, 0.f);
    float2 a3 = make_float2(0.f, 0.f);

    const int kmax = (u < 64) ? u : 64;
    int k = 0;
    for (; k + 3 < kmax; k += 4) {
        int j0 = __shfl(nl0, k),     j1 = __shfl(nl0, k + 1);
        int j2 = __shfl(nl0, k + 2), j3 = __shfl(nl0, k + 3);
        float s0 = __shfl(nd0, k),     s1 = __shfl(nd0, k + 1);
        float s2 = __shfl(nd0, k + 2), s3 = __shfl(nd0, k + 3);
        float2 v0 = __half22float2(h2[(size_t)j0 * 64 + lane]);
        float2 v1 = __half22float2(h2[(size_t)j1 * 64 + lane]);
        float2 v2 = __half22float2(h2[(size_t)j2 * 64 + lane]);
        float2 v3 = __half22float2(h2[(size_t)j3 * 64 + lane]);
        a0.x += s0 * v0.x; a0.y += s0 * v0.y;
        a1.x += s1 * v1.x; a1.y += s1 * v1.y;
        a2.x += s2 * v2.x; a2.y += s2 * v2.y;
        a3.x += s3 * v3.x; a3.y += s3 * v3.y;
    }
    for (; k < kmax; ++k) {
        int j0 = __shfl(nl0, k);
        float s0 = __shfl(nd0, k);
        float2 v0 = __half22float2(h2[(size_t)j0 * 64 + lane]);
        a0.x += s0 * v0.x; a0.y += s0 * v0.y;
    }
    for (k = 64; k < u; ++k) {           // rare: u > 64
        int j0 = __shfl(nl1, k - 64);
        float s0 = __shfl(nd1, k - 64);
        float2 v0 = __half22float2(h2[(size_t)j0 * 64 + lane]);
        a0.x += s0 * v0.x; a0.y += s0 * v0.y;
    }

    float2 acc;
    acc.x = (a0.x + a1.x) + (a2.x + a3.x);
    acc.y = (a0.y + a1.y) + (a2.y + a3.y);
    const float di = dinv[row];
    float2 hv = __half22float2(h2[(size_t)row * 64 + lane]);
    float2 o;
    o.x = di * (acc.x + di * hv.x);
    o.y = di * (acc.y + di * hv.y);
    *(float2*)&out[(size_t)row * DD + lane * 2] = o;
}

extern "C" void kernel_launch(void* const* d_in, const int* in_sizes, int n_in,
                              void* d_out, int out_size, void* d_ws, size_t ws_size,
                              hipStream_t stream) {
    const float* x  = (const float*)d_in[0];
    const int*   ei = (const int*)d_in[1];
    const float* Wm = (const float*)d_in[2];
    const float* bs = (const float*)d_in[3];
    float* out = (float*)d_out;
    const int E = in_sizes[1] / 2;

    // workspace (~8.2 MB)
    char* p = (char*)d_ws;
    int* cnt    = (int*)p;   p += (size_t)NN * sizeof(int);           // 32 KB
    int* ucnt   = (int*)p;   p += (size_t)NN * sizeof(int);           // 32 KB
    float* dinv = (float*)p; p += (size_t)NN * sizeof(float);         // 32 KB
    int* adj    = (int*)p;   p += (size_t)NN * RCAP * sizeof(int);    // 3 MB
    int* uadj   = (int*)p;   p += (size_t)NN * RCAP * sizeof(int);    // 3 MB
    __half* h   = (__half*)p;                                         // 2 MB

    linear_kernel<<<1024, 64, 0, stream>>>(x, Wm, bs, cnt, h);        // also zeroes cnt
    scatter_kernel<<<(E + 255) / 256, 256, 0, stream>>>(ei, E, cnt, adj);
    dedup_kernel<<<NN / 4, 256, 0, stream>>>(cnt, adj, uadj, ucnt, dinv);
    agg_kernel<<<NN / 4, 256, 0, stream>>>(ucnt, uadj, dinv, h, out);
}